// Round 1
// baseline (2766.605 us; speedup 1.0000x reference)
//
#include <hip/hip_runtime.h>

#define D_DIM  784
#define HID    256
#define MD     16
#define ROWS   16
#define KC     32
#define NT     256
#define XS_STR 20   // padded stride for [k][row] X tile (16B-aligned rows)
#define HS_STR 20   // padded stride for [c][row] H tile
// Augmented 16x17 system per batch row, stride-17 rows, 272 floats per row.
#define MS(r,i,j) Msb[(r)*272 + (i)*17 + (j)]

__global__ __launch_bounds__(NT, 2)
void riemann_fused(const float* __restrict__ x,  const float* __restrict__ tvec,
                   const float* __restrict__ W1, const float* __restrict__ b1,
                   const float* __restrict__ W2, const float* __restrict__ b2,
                   const float* __restrict__ Wp, const float* __restrict__ bp,
                   const float* __restrict__ Wl, const float* __restrict__ bl,
                   float* __restrict__ out)
{
    // LDS budget (phase-aliased): 2560 + 32768 + 20480 + 2048 + 1024 + 1024 = 59904 B
    __shared__ float Xst[KC * XS_STR];     // X chunk, transposed [k][row]
    __shared__ float WsBuf[8192];          // W1/W2 chunk -> A (g_flat) -> Wl chunk
    __shared__ float Hst[HID * HS_STR];    // H transposed [c][row]; later aliased as Ms
    __shared__ float Wps[KC * MD];         // Wp chunk
    __shared__ float xis[ROWS * MD];       // xi
    __shared__ float ysb[ROWS * MD];       // solve result y
    float* Msb = Hst;                      // augmented systems alias (4352f <= 5120f)

    const int tid  = threadIdx.x;
    const int wv   = tid >> 6;             // wave id 0..3 -> 4 batch rows each
    const int c0   = (tid & 63) << 2;      // 4 output cols per lane (0..252)
    const int r0w  = wv << 2;              // first batch row of this wave's micro-tile
    const int row0 = blockIdx.x * ROWS;
    const int xr   = tid >> 4;             // 0..15 (row for xi / solve / rhs)
    const int xc   = tid & 15;             // 0..15 (col for xi / solve / rhs)

    float acc[4][4];
#pragma unroll
    for (int i = 0; i < 4; i++)
#pragma unroll
        for (int j = 0; j < 4; j++) acc[i][j] = 0.0f;
    float xia = 0.0f;

    // ---------------- Phase 1: H = relu(X W1 + b1), xi = X Wp + bp ----------------
    for (int kc = 0; kc < D_DIM; kc += KC) {
        const int rem = (D_DIM - kc < KC) ? (D_DIM - kc) : KC;
        // X chunk (transposed store), 512 elems, zero-fill tail
#pragma unroll
        for (int i = 0; i < 2; i++) {
            int idx = tid + NT * i;
            int r = idx >> 5, k = idx & 31;
            Xst[k * XS_STR + r] = (k < rem) ? x[(row0 + r) * D_DIM + kc + k] : 0.0f;
        }
        // Wp chunk, 512 elems
#pragma unroll
        for (int i = 0; i < 2; i++) {
            int idx = tid + NT * i;
            int k = idx >> 4, c = idx & 15;
            Wps[k * MD + c] = (k < rem) ? Wp[(kc + k) * MD + c] : 0.0f;
        }
        // W1 chunk, 8192 elems (coalesced)
        if (rem == KC) {
#pragma unroll
            for (int i = 0; i < 32; i++) {
                int idx = tid + NT * i;
                int k = idx >> 8, c = idx & 255;
                WsBuf[idx] = W1[(kc + k) * HID + c];
            }
        } else {
#pragma unroll
            for (int i = 0; i < 32; i++) {
                int idx = tid + NT * i;
                int k = idx >> 8, c = idx & 255;
                WsBuf[idx] = (k < rem) ? W1[(kc + k) * HID + c] : 0.0f;
            }
        }
        __syncthreads();
#pragma unroll
        for (int k = 0; k < KC; k++) {
            const float4 xv = *(const float4*)&Xst[k * XS_STR + r0w];   // broadcast b128
            const float4 w  = *(const float4*)&WsBuf[k * HID + c0];     // contiguous b128
            const float xa[4] = {xv.x, xv.y, xv.z, xv.w};
            const float wa[4] = {w.x, w.y, w.z, w.w};
#pragma unroll
            for (int i = 0; i < 4; i++)
#pragma unroll
                for (int j = 0; j < 4; j++) acc[i][j] += xa[i] * wa[j];
            xia += Xst[k * XS_STR + xr] * Wps[k * MD + xc];
        }
        __syncthreads();
    }
    // bias + relu, store H transposed [c][row]
    {
        const float4 bv = *(const float4*)&b1[c0];
        const float ba[4] = {bv.x, bv.y, bv.z, bv.w};
#pragma unroll
        for (int j = 0; j < 4; j++) {
            float4 h;
            float v0 = acc[0][j] + ba[j]; h.x = v0 > 0.0f ? v0 : 0.0f;
            float v1 = acc[1][j] + ba[j]; h.y = v1 > 0.0f ? v1 : 0.0f;
            float v2 = acc[2][j] + ba[j]; h.z = v2 > 0.0f ? v2 : 0.0f;
            float v3 = acc[3][j] + ba[j]; h.w = v3 > 0.0f ? v3 : 0.0f;
            *(float4*)&Hst[(c0 + j) * HS_STR + r0w] = h;
        }
        xis[xr * MD + xc] = xia + bp[xc];
    }
    __syncthreads();

    // ---------------- Phase 2: g_flat = H W2 + b2 ----------------
    float acc2[4][4];
#pragma unroll
    for (int i = 0; i < 4; i++)
#pragma unroll
        for (int j = 0; j < 4; j++) acc2[i][j] = 0.0f;

    for (int kc = 0; kc < HID; kc += KC) {
#pragma unroll
        for (int i = 0; i < 32; i++) {
            int idx = tid + NT * i;
            int k = idx >> 8, c = idx & 255;
            WsBuf[idx] = W2[(kc + k) * HID + c];
        }
        __syncthreads();
#pragma unroll
        for (int k = 0; k < KC; k++) {
            const float4 hv = *(const float4*)&Hst[(kc + k) * HS_STR + r0w];
            const float4 w  = *(const float4*)&WsBuf[k * HID + c0];
            const float ha[4] = {hv.x, hv.y, hv.z, hv.w};
            const float wa[4] = {w.x, w.y, w.z, w.w};
#pragma unroll
            for (int i = 0; i < 4; i++)
#pragma unroll
                for (int j = 0; j < 4; j++) acc2[i][j] += ha[i] * wa[j];
        }
        __syncthreads();
    }
    // store A = g_flat + b2 into WsBuf as [row][256]
    {
        const float4 bv = *(const float4*)&b2[c0];
#pragma unroll
        for (int i = 0; i < 4; i++) {
            float4 a;
            a.x = acc2[i][0] + bv.x;
            a.y = acc2[i][1] + bv.y;
            a.z = acc2[i][2] + bv.z;
            a.w = acc2[i][3] + bv.w;
            *(float4*)&WsBuf[(r0w + i) * HID + c0] = a;
        }
    }
    __syncthreads();

    // ---------------- Phase 3: g = A A^T + 0.1 I, rhs = -xi/(t+1e-6) ----------------
    // (writes augmented systems into Msb, which aliases the now-dead Hst)
#pragma unroll
    for (int it = 0; it < 16; ++it) {
        int idx = tid + NT * it;              // 0..4095 : 16 rows x 256 (i,j) pairs
        int r = idx >> 8;
        int i = (idx >> 4) & 15;
        int j = idx & 15;
        const float4* Ai = (const float4*)&WsBuf[r * HID + i * MD];
        const float4* Aj = (const float4*)&WsBuf[r * HID + j * MD];
        float s = (i == j) ? 0.1f : 0.0f;
#pragma unroll
        for (int m = 0; m < 4; m++) {
            float4 a = Ai[m], b = Aj[m];
            s += a.x * b.x + a.y * b.y + a.z * b.z + a.w * b.w;
        }
        MS(r, i, j) = s;
    }
    MS(xr, xc, 16) = -xis[xr * MD + xc] / (tvec[row0 + xr] + 1e-6f);
    __syncthreads();

    // ---------------- Phase 4: Gauss-Jordan solve (SPD, no pivoting) ----------------
    // 16 threads per batch row, one matrix-row each; 16 barrier steps.
    for (int k = 0; k < MD; k++) {
        if (xc != k) {
            float piv = MS(xr, k, k);
            float f = MS(xr, xc, k) / piv;
            for (int j = k + 1; j <= 16; j++)
                MS(xr, xc, j) -= f * MS(xr, k, j);
        }
        __syncthreads();
    }
    ysb[xr * MD + xc] = MS(xr, xc, 16) / MS(xr, xc, xc);
    __syncthreads();

    // ---------------- Phase 5: out = y Wl + bl ----------------
    for (int cc = 0; cc < 2; ++cc) {
        __syncthreads();                       // protect WsBuf reuse
#pragma unroll
        for (int it = 0; it < 25; ++it) {
            int idx = tid + NT * it;
            if (idx < MD * 392) {
                int k = idx / 392;
                int c = idx - k * 392;
                WsBuf[idx] = Wl[k * D_DIM + cc * 392 + c];
            }
        }
        __syncthreads();
#pragma unroll
        for (int it = 0; it < 25; ++it) {
            int idx = tid + NT * it;
            if (idx < ROWS * 392) {
                int r = idx / 392;
                int c = idx - r * 392;
                int gc = cc * 392 + c;
                float s = bl[gc];
#pragma unroll
                for (int k = 0; k < MD; k++)
                    s += ysb[r * MD + k] * WsBuf[k * 392 + c];
                out[(row0 + r) * D_DIM + gc] = s;
            }
        }
    }
}

extern "C" void kernel_launch(void* const* d_in, const int* in_sizes, int n_in,
                              void* d_out, int out_size, void* d_ws, size_t ws_size,
                              hipStream_t stream) {
    (void)n_in; (void)out_size; (void)d_ws; (void)ws_size;
    const float* x  = (const float*)d_in[0];
    const float* t  = (const float*)d_in[1];
    const float* W1 = (const float*)d_in[2];
    const float* b1 = (const float*)d_in[3];
    const float* W2 = (const float*)d_in[4];
    const float* b2 = (const float*)d_in[5];
    const float* Wp = (const float*)d_in[6];
    const float* bp = (const float*)d_in[7];
    const float* Wl = (const float*)d_in[8];
    const float* bl = (const float*)d_in[9];
    float* out = (float*)d_out;

    const int B = in_sizes[1];              // 131072 (t has one element per row)
    dim3 grid(B / ROWS), block(NT);
    hipLaunchKernelGGL(riemann_fused, grid, block, 0, stream,
                       x, t, W1, b1, W2, b2, Wp, bp, Wl, bl, out);
}